// Round 6
// baseline (364.363 us; speedup 1.0000x reference)
//
#include <hip/hip_runtime.h>
#include <hip/hip_bf16.h>
#include <stdint.h>

#define DIM   1024
#define TLEN  2048
#define HD    64
#define MROWS 8192   // B*T

typedef __bf16 bf16x8 __attribute__((ext_vector_type(8)));
typedef float  f32x4  __attribute__((ext_vector_type(4)));

union PFrag { uint32_t w[4]; bf16x8 v; };

__device__ __forceinline__ uint32_t bf16rnd(float f){
  uint32_t u = __builtin_bit_cast(uint32_t, f);
  return (u + 0x7FFFu + ((u >> 16) & 1u)) >> 16;
}
// packed RNE convert: emits v_cvt_pk_bf16_f32 (low = a, high = b)
__device__ __forceinline__ uint32_t pack2(float a, float b){
  float2 t; t.x = a; t.y = b;
  __hip_bfloat162 h = __float22bfloat162_rn(t);
  uint32_t r;
  __builtin_memcpy(&r, &h, 4);
  return r;
}

#define GLDS(g, l) __builtin_amdgcn_global_load_lds( \
    (const __attribute__((address_space(1))) void*)(g), \
    (__attribute__((address_space(3))) void*)(l), 16, 0, 0)

// ---------------------------------------------------------------- convert (4 weights in one launch)
__global__ __launch_bounds__(256) void cvt_kernel(
    const float* __restrict__ s0, const float* __restrict__ s1,
    const float* __restrict__ s2, const float* __restrict__ s3,
    uint16_t* __restrict__ d0, uint16_t* __restrict__ d1,
    uint16_t* __restrict__ d2, uint16_t* __restrict__ d3)
{
  const float* src; uint16_t* dst;
  if (blockIdx.y == 0){ src = s0; dst = d0; }
  else if (blockIdx.y == 1){ src = s1; dst = d1; }
  else if (blockIdx.y == 2){ src = s2; dst = d2; }
  else { src = s3; dst = d3; }
  const int i = blockIdx.x * 256 + threadIdx.x;
  const float4 f = *reinterpret_cast<const float4*>(src + (size_t)i * 4);
  uint32_t* d = reinterpret_cast<uint32_t*>(dst + (size_t)i * 4);
  d[0] = pack2(f.x, f.y);
  d[1] = pack2(f.z, f.w);
}

// ---------------------------------------------------------------- layernorm
__global__ __launch_bounds__(256) void ln_kernel(
    const float* __restrict__ x, const float* __restrict__ gamma,
    const float* __restrict__ beta, uint16_t* __restrict__ xn)
{
  const int row = blockIdx.x;
  const int tid = threadIdx.x;
  const float4 v = *reinterpret_cast<const float4*>(x + (size_t)row * DIM + tid * 4);
  float s  = (v.x + v.y) + (v.z + v.w);
  float ss = (v.x * v.x + v.y * v.y) + (v.z * v.z + v.w * v.w);
#pragma unroll
  for (int off = 1; off < 64; off <<= 1){
    s  += __shfl_xor(s, off);
    ss += __shfl_xor(ss, off);
  }
  __shared__ float red[8];
  if ((tid & 63) == 0){ red[tid >> 6] = s; red[(tid >> 6) + 4] = ss; }
  __syncthreads();
  s  = (red[0] + red[1]) + (red[2] + red[3]);
  ss = (red[4] + red[5]) + (red[6] + red[7]);
  const float mu   = s * (1.0f / DIM);
  const float var  = ss * (1.0f / DIM) - mu * mu;
  const float rstd = rsqrtf(var + 1e-5f);
  const float4 g  = *reinterpret_cast<const float4*>(gamma + tid * 4);
  const float4 bt = *reinterpret_cast<const float4*>(beta  + tid * 4);
  const float o0 = (v.x - mu) * rstd * g.x + bt.x;
  const float o1 = (v.y - mu) * rstd * g.y + bt.y;
  const float o2 = (v.z - mu) * rstd * g.z + bt.z;
  const float o3 = (v.w - mu) * rstd * g.w + bt.w;
  uint32_t* dst = reinterpret_cast<uint32_t*>(xn + (size_t)row * DIM + tid * 4);
  dst[0] = pack2(o0, o1);
  dst[1] = pack2(o2, o3);
}

// ---------------------------------------------------------------- GEMM (NT: C = A @ W^T)
template<int EPI>
__device__ __forceinline__ void gemm_body(
    const uint16_t* __restrict__ A, const uint16_t* __restrict__ W,
    const float* __restrict__ bias,
    uint16_t* __restrict__ Cb, float* __restrict__ Cf,
    const float* __restrict__ res, float scale)
{
  __shared__ uint16_t As[128 * 32];
  __shared__ uint16_t Bs[128 * 32];
  const int tid  = threadIdx.x;
  const int lane = tid & 63;
  const int w    = tid >> 6;
  const int wr   = w >> 1, wc = w & 1;
  const int row0 = blockIdx.y * 128;
  const int col0 = blockIdx.x * 128;

  f32x4 acc[4][4] = {};

  const int srow = lane >> 2;        // 0..15
  const int scol = (lane & 3) * 8;   // 0,8,16,24
  const uint16_t* a0 = A + (size_t)(row0 + w * 32 + srow) * DIM + scol;
  const uint16_t* a1 = a0 + (size_t)16 * DIM;
  const uint16_t* b0 = W + (size_t)(col0 + w * 32 + srow) * DIM + scol;
  const uint16_t* b1 = b0 + (size_t)16 * DIM;
  uint16_t* la0 = &As[w * 1024];
  uint16_t* la1 = &As[w * 1024 + 512];
  uint16_t* lb0 = &Bs[w * 1024];
  uint16_t* lb1 = &Bs[w * 1024 + 512];

  const int fr = lane & 15, fg = lane >> 4;

  for (int k0 = 0; k0 < DIM; k0 += 32){
    GLDS(a0 + k0, la0);
    GLDS(a1 + k0, la1);
    GLDS(b0 + k0, lb0);
    GLDS(b1 + k0, lb1);
    __syncthreads();
    bf16x8 af[4], bfv[4];
#pragma unroll
    for (int m = 0; m < 4; ++m)
      af[m] = *reinterpret_cast<const bf16x8*>(&As[(wr * 64 + m * 16 + fr) * 32 + fg * 8]);
#pragma unroll
    for (int n = 0; n < 4; ++n)
      bfv[n] = *reinterpret_cast<const bf16x8*>(&Bs[(wc * 64 + n * 16 + fr) * 32 + fg * 8]);
#pragma unroll
    for (int m = 0; m < 4; ++m)
#pragma unroll
      for (int n = 0; n < 4; ++n)
        acc[m][n] = __builtin_amdgcn_mfma_f32_16x16x32_bf16(af[m], bfv[n], acc[m][n], 0, 0, 0);
    __syncthreads();
  }

#pragma unroll
  for (int m = 0; m < 4; ++m){
    const int rbase = row0 + wr * 64 + m * 16 + fg * 4;
#pragma unroll
    for (int n = 0; n < 4; ++n){
      const int c = col0 + wc * 64 + n * 16 + fr;
      const float bv = bias[c];
      if (EPI == 0){
#pragma unroll
        for (int r = 0; r < 4; ++r){
          float v = (acc[m][n][r] + bv) * scale;
          Cb[(size_t)(rbase + r) * DIM + c] = (uint16_t)bf16rnd(v);
        }
      } else {
#pragma unroll
        for (int r = 0; r < 4; ++r){
          size_t idx = (size_t)(rbase + r) * DIM + c;
          Cf[idx] = acc[m][n][r] + bv + res[idx];
        }
      }
    }
  }
}

__global__ __launch_bounds__(256) void qkv_gemm(
    const uint16_t* __restrict__ xn,
    const uint16_t* __restrict__ Wq, const uint16_t* __restrict__ Wk,
    const uint16_t* __restrict__ Wv,
    const float* __restrict__ bq, const float* __restrict__ bk,
    const float* __restrict__ bv,
    uint16_t* __restrict__ Qo, uint16_t* __restrict__ Ko, uint16_t* __restrict__ Vo)
{
  const uint16_t* W; const float* bias; uint16_t* out; float scale;
  if (blockIdx.z == 0){ W = Wq; bias = bq; out = Qo; scale = 0.125f; }  // 1/sqrt(hd) folded into Q
  else if (blockIdx.z == 1){ W = Wk; bias = bk; out = Ko; scale = 1.0f; }
  else { W = Wv; bias = bv; out = Vo; scale = 1.0f; }
  gemm_body<0>(xn, W, bias, out, nullptr, nullptr, scale);
}

__global__ __launch_bounds__(256) void out_gemm(
    const uint16_t* __restrict__ AO, const uint16_t* __restrict__ Wo,
    const float* __restrict__ bo, const float* __restrict__ res,
    float* __restrict__ out)
{
  gemm_body<1>(AO, Wo, bo, nullptr, out, res, 1.0f);
}

// ---------------------------------------------------------------- causal flash attention
// R4 datapath + (1) length-mixing p-swizzle: p_eff=(x+4z)&15 so each CU's
// resident blocks have mixed iteration counts; (2) K-fragment LDS reads
// hoisted out of step (shared by both q-tiles); (3) V stage-writes as 4xb64;
// (4) cvt_pk packing. __launch_bounds__(256,4) pins VGPR <= 128.
__global__ __launch_bounds__(256, 4) void attn_kernel(
    const uint16_t* __restrict__ Q, const uint16_t* __restrict__ K,
    const uint16_t* __restrict__ V, uint16_t* __restrict__ O)
{
  __shared__ uint16_t Kl[64 * 72];
  __shared__ uint16_t Vt[64 * 72];
  const int tid  = threadIdx.x;
  const int lane = tid & 63;
  const int w    = tid >> 6;
  const int fr   = lane & 15, fg = lane >> 4;
  const int b = blockIdx.z, h = blockIdx.y;
  const int p = (blockIdx.x + 4 * blockIdx.z) & 15;   // length-mixing swizzle
  const int qtA = p, qtB = 31 - p;
  const size_t rowb = (size_t)b * TLEN;
  const int hoff = h * HD;

  const int qgA = qtA * 64 + w * 16 + fr;
  const int qgB = qtB * 64 + w * 16 + fr;

  const bf16x8 qA0 = *reinterpret_cast<const bf16x8*>(Q + (rowb + qgA) * DIM + hoff + fg * 8);
  const bf16x8 qA1 = *reinterpret_cast<const bf16x8*>(Q + (rowb + qgA) * DIM + hoff + 32 + fg * 8);
  const bf16x8 qB0 = *reinterpret_cast<const bf16x8*>(Q + (rowb + qgB) * DIM + hoff + fg * 8);
  const bf16x8 qB1 = *reinterpret_cast<const bf16x8*>(Q + (rowb + qgB) * DIM + hoff + 32 + fg * 8);

  f32x4 oA[4] = {}, oB[4] = {};
  float mA = -1e30f, lA = 0.0f, mB = -1e30f, lB = 0.0f;

  const int kr = tid >> 2, kc = (tid & 3) * 16;   // K staging
  const int vd = tid & 63, vq = tid >> 6;         // V staging (transpose)
  const int vf = ((vd >> 3) & 7) << 3;            // write-side swizzle

  const uint16_t* kbase = K + (rowb + kr) * DIM + hoff + kc;
  const uint16_t* vbase = V + (rowb + vq * 16) * DIM + hoff + vd;

  bf16x8 kst0, kst1;
  uint16_t vst[16];

  auto load_tile = [&](int kt, bf16x8& k0, bf16x8& k1, uint16_t (&vr)[16]){
    const size_t koff = (size_t)kt * 64 * DIM;
    k0 = *reinterpret_cast<const bf16x8*>(kbase + koff);
    k1 = *reinterpret_cast<const bf16x8*>(kbase + koff + 8);
    const uint16_t* vsrc = vbase + koff;
#pragma unroll
    for (int kk = 0; kk < 16; ++kk)
      vr[kk] = vsrc[(size_t)kk * DIM];
  };

  load_tile(0, kst0, kst1, vst);

  for (int kt = 0; kt <= qtB; ++kt){
    const int kv0 = kt * 64;
    // write staged registers to LDS (V as 4 x b64; XOR bits>=3 keep 4-u16 runs contiguous)
    *reinterpret_cast<bf16x8*>(&Kl[kr * 72 + kc])     = kst0;
    *reinterpret_cast<bf16x8*>(&Kl[kr * 72 + kc + 8]) = kst1;
#pragma unroll
    for (int j = 0; j < 4; ++j){
      const uint64_t q0 = (uint64_t)vst[4 * j]     | ((uint64_t)vst[4 * j + 1] << 16)
                        | ((uint64_t)vst[4 * j + 2] << 32) | ((uint64_t)vst[4 * j + 3] << 48);
      *reinterpret_cast<uint64_t*>(&Vt[vd * 72 + ((vq * 16 + 4 * j) ^ vf)]) = q0;
    }
    __syncthreads();

    // issue next tile's global loads (latency hidden under compute)
    bf16x8 nk0, nk1;
    uint16_t nv[16];
    if (kt < qtB) load_tile(kt + 1, nk0, nk1, nv);

    // K fragments hoisted: shared by both q-steps this iteration
    bf16x8 kf0[4], kf1[4];
#pragma unroll
    for (int t = 0; t < 4; ++t){
      kf0[t] = *reinterpret_cast<const bf16x8*>(&Kl[(t * 16 + fr) * 72 + fg * 8]);
      kf1[t] = *reinterpret_cast<const bf16x8*>(&Kl[(t * 16 + fr) * 72 + 32 + fg * 8]);
    }

    auto step = [&](const bf16x8& q0, const bf16x8& q1, f32x4 (&oacc)[4],
                    float& mr, float& lr, const int qg, const bool diag){
      f32x4 s[4];
#pragma unroll
      for (int t = 0; t < 4; ++t){
        f32x4 z = {};
        z = __builtin_amdgcn_mfma_f32_16x16x32_bf16(kf0[t], q0, z, 0, 0, 0);
        z = __builtin_amdgcn_mfma_f32_16x16x32_bf16(kf1[t], q1, z, 0, 0, 0);
        s[t] = z;
      }

      float mloc = -1e30f;
      if (diag){
#pragma unroll
        for (int t = 0; t < 4; ++t)
#pragma unroll
          for (int r = 0; r < 4; ++r){
            const int kvg = kv0 + t * 16 + fg * 4 + r;
            const float sv = (kvg <= qg) ? s[t][r] : -1e30f;
            s[t][r] = sv;
            mloc = fmaxf(mloc, sv);
          }
      } else {
#pragma unroll
        for (int t = 0; t < 4; ++t)
#pragma unroll
          for (int r = 0; r < 4; ++r) mloc = fmaxf(mloc, s[t][r]);
      }
      mloc = fmaxf(mloc, __shfl_xor(mloc, 16));
      mloc = fmaxf(mloc, __shfl_xor(mloc, 32));

      // T13 defer-max: only rescale when the max moved by > 8
      if (mloc > mr + 8.0f){
        const float alpha = __expf(mr - mloc);
        mr = mloc;
        lr *= alpha;
#pragma unroll
        for (int dt = 0; dt < 4; ++dt) oacc[dt] *= alpha;
      }

      uint32_t plo[4], phi[4];
      float psum = 0.0f;
#pragma unroll
      for (int t = 0; t < 4; ++t){
        const float p0 = __expf(s[t][0] - mr);
        const float p1 = __expf(s[t][1] - mr);
        const float p2 = __expf(s[t][2] - mr);
        const float p3 = __expf(s[t][3] - mr);
        psum += (p0 + p1) + (p2 + p3);
        plo[t] = pack2(p0, p1);
        phi[t] = pack2(p2, p3);
      }
      psum += __shfl_xor(psum, 16);
      psum += __shfl_xor(psum, 32);
      lr += psum;

      // P^T B-fragments via cross-lane redistribution (8 shuffles per 32-kv block)
      const int  src0 = fr + ((lane >> 4) & 1) * 32;
      const bool hi   = lane >= 32;
#pragma unroll
      for (int kb = 0; kb < 2; ++kb){
        const uint32_t la  = (uint32_t)__shfl((int)plo[2 * kb],     src0);
        const uint32_t lb  = (uint32_t)__shfl((int)plo[2 * kb + 1], src0);
        const uint32_t ha  = (uint32_t)__shfl((int)phi[2 * kb],     src0);
        const uint32_t hb  = (uint32_t)__shfl((int)phi[2 * kb + 1], src0);
        const uint32_t la2 = (uint32_t)__shfl((int)plo[2 * kb],     src0 + 16);
        const uint32_t lb2 = (uint32_t)__shfl((int)plo[2 * kb + 1], src0 + 16);
        const uint32_t ha2 = (uint32_t)__shfl((int)phi[2 * kb],     src0 + 16);
        const uint32_t hb2 = (uint32_t)__shfl((int)phi[2 * kb + 1], src0 + 16);
        PFrag pf;
        pf.w[0] = hi ? lb  : la;
        pf.w[1] = hi ? hb  : ha;
        pf.w[2] = hi ? lb2 : la2;
        pf.w[3] = hi ? hb2 : ha2;
#pragma unroll
        for (int dt = 0; dt < 4; ++dt){
          const int d = dt * 16 + fr;
          const int f = ((d >> 3) & 7) << 3;
          const bf16x8 vfr = *reinterpret_cast<const bf16x8*>(
              &Vt[d * 72 + ((kb * 32 + fg * 8) ^ f)]);
          oacc[dt] = __builtin_amdgcn_mfma_f32_16x16x32_bf16(vfr, pf.v, oacc[dt], 0, 0, 0);
        }
      }
    };

    if (kt <= qtA) step(qA0, qA1, oA, mA, lA, qgA, kt == qtA);
    step(qB0, qB1, oB, mB, lB, qgB, kt == qtB);
    __syncthreads();

    if (kt < qtB){
      kst0 = nk0; kst1 = nk1;
#pragma unroll
      for (int kk = 0; kk < 16; ++kk) vst[kk] = nv[kk];
    }
  }

  const float invA = 1.0f / lA;
  const float invB = 1.0f / lB;
#pragma unroll
  for (int dt = 0; dt < 4; ++dt){
    uint32_t* dstA = reinterpret_cast<uint32_t*>(
        O + (rowb + qgA) * DIM + hoff + dt * 16 + fg * 4);
    dstA[0] = pack2(oA[dt][0] * invA, oA[dt][1] * invA);
    dstA[1] = pack2(oA[dt][2] * invA, oA[dt][3] * invA);
    uint32_t* dstB = reinterpret_cast<uint32_t*>(
        O + (rowb + qgB) * DIM + hoff + dt * 16 + fg * 4);
    dstB[0] = pack2(oB[dt][0] * invB, oB[dt][1] * invB);
    dstB[1] = pack2(oB[dt][2] * invB, oB[dt][3] * invB);
  }
}

// ---------------------------------------------------------------- launch
extern "C" void kernel_launch(void* const* d_in, const int* in_sizes, int n_in,
                              void* d_out, int out_size, void* d_ws, size_t ws_size,
                              hipStream_t stream) {
  const float* x     = (const float*)d_in[0];
  const float* Wq    = (const float*)d_in[1];
  const float* bq    = (const float*)d_in[2];
  const float* Wk    = (const float*)d_in[3];
  const float* bk    = (const float*)d_in[4];
  const float* Wv    = (const float*)d_in[5];
  const float* bv    = (const float*)d_in[6];
  const float* Wo    = (const float*)d_in[7];
  const float* bo    = (const float*)d_in[8];
  const float* gamma = (const float*)d_in[9];
  const float* beta  = (const float*)d_in[10];
  float* out = (float*)d_out;

  uint8_t* ws = (uint8_t*)d_ws;
  uint16_t* xn  = (uint16_t*)(ws);                                  // 16 MB
  uint16_t* Wqb = (uint16_t*)(ws + 16777216);                       // 2 MB each
  uint16_t* Wkb = (uint16_t*)(ws + 16777216 + 1 * 2097152);
  uint16_t* Wvb = (uint16_t*)(ws + 16777216 + 2 * 2097152);
  uint16_t* Wob = (uint16_t*)(ws + 16777216 + 3 * 2097152);
  uint16_t* Qb  = (uint16_t*)(ws + 25165824);                       // 16 MB each
  uint16_t* Kb  = (uint16_t*)(ws + 25165824 + 1 * 16777216);
  uint16_t* Vb  = (uint16_t*)(ws + 25165824 + 2 * 16777216);
  uint16_t* AOb = (uint16_t*)(ws + 25165824 + 3 * 16777216);

  cvt_kernel<<<dim3(1024, 4), 256, 0, stream>>>(Wq, Wk, Wv, Wo, Wqb, Wkb, Wvb, Wob);
  ln_kernel<<<8192, 256, 0, stream>>>(x, gamma, beta, xn);
  qkv_gemm<<<dim3(8, 64, 3), 256, 0, stream>>>(xn, Wqb, Wkb, Wvb, bq, bk, bv, Qb, Kb, Vb);
  attn_kernel<<<dim3(16, 16, 4), 256, 0, stream>>>(Qb, Kb, Vb, AOb);
  out_gemm<<<dim3(8, 64, 1), 256, 0, stream>>>(AOb, Wob, bo, x, out);
}

// Round 8
// 318.736 us; speedup vs baseline: 1.1432x; 1.1432x over previous
//
#include <hip/hip_runtime.h>
#include <hip/hip_bf16.h>
#include <stdint.h>

#define DIM   1024
#define TLEN  2048
#define HD    64
#define MROWS 8192   // B*T

typedef __bf16 bf16x8 __attribute__((ext_vector_type(8)));
typedef float  f32x4  __attribute__((ext_vector_type(4)));

union PFrag { uint32_t w[4]; bf16x8 v; };

__device__ __forceinline__ uint32_t bf16rnd(float f){
  uint32_t u = __builtin_bit_cast(uint32_t, f);
  return (u + 0x7FFFu + ((u >> 16) & 1u)) >> 16;
}
// packed RNE convert: emits v_cvt_pk_bf16_f32 (low = a, high = b)
__device__ __forceinline__ uint32_t pack2(float a, float b){
  float2 t; t.x = a; t.y = b;
  __hip_bfloat162 h = __float22bfloat162_rn(t);
  uint32_t r;
  __builtin_memcpy(&r, &h, 4);
  return r;
}

#define GLDS(g, l) __builtin_amdgcn_global_load_lds( \
    (const __attribute__((address_space(1))) void*)(g), \
    (__attribute__((address_space(3))) void*)(l), 16, 0, 0)

// ---------------------------------------------------------------- convert (4 weights in one launch)
__global__ __launch_bounds__(256) void cvt_kernel(
    const float* __restrict__ s0, const float* __restrict__ s1,
    const float* __restrict__ s2, const float* __restrict__ s3,
    uint16_t* __restrict__ d0, uint16_t* __restrict__ d1,
    uint16_t* __restrict__ d2, uint16_t* __restrict__ d3)
{
  const float* src; uint16_t* dst;
  if (blockIdx.y == 0){ src = s0; dst = d0; }
  else if (blockIdx.y == 1){ src = s1; dst = d1; }
  else if (blockIdx.y == 2){ src = s2; dst = d2; }
  else { src = s3; dst = d3; }
  const int i = blockIdx.x * 256 + threadIdx.x;
  const float4 f = *reinterpret_cast<const float4*>(src + (size_t)i * 4);
  uint32_t* d = reinterpret_cast<uint32_t*>(dst + (size_t)i * 4);
  d[0] = pack2(f.x, f.y);
  d[1] = pack2(f.z, f.w);
}

// ---------------------------------------------------------------- layernorm
__global__ __launch_bounds__(256) void ln_kernel(
    const float* __restrict__ x, const float* __restrict__ gamma,
    const float* __restrict__ beta, uint16_t* __restrict__ xn)
{
  const int row = blockIdx.x;
  const int tid = threadIdx.x;
  const float4 v = *reinterpret_cast<const float4*>(x + (size_t)row * DIM + tid * 4);
  float s  = (v.x + v.y) + (v.z + v.w);
  float ss = (v.x * v.x + v.y * v.y) + (v.z * v.z + v.w * v.w);
#pragma unroll
  for (int off = 1; off < 64; off <<= 1){
    s  += __shfl_xor(s, off);
    ss += __shfl_xor(ss, off);
  }
  __shared__ float red[8];
  if ((tid & 63) == 0){ red[tid >> 6] = s; red[(tid >> 6) + 4] = ss; }
  __syncthreads();
  s  = (red[0] + red[1]) + (red[2] + red[3]);
  ss = (red[4] + red[5]) + (red[6] + red[7]);
  const float mu   = s * (1.0f / DIM);
  const float var  = ss * (1.0f / DIM) - mu * mu;
  const float rstd = rsqrtf(var + 1e-5f);
  const float4 g  = *reinterpret_cast<const float4*>(gamma + tid * 4);
  const float4 bt = *reinterpret_cast<const float4*>(beta  + tid * 4);
  const float o0 = (v.x - mu) * rstd * g.x + bt.x;
  const float o1 = (v.y - mu) * rstd * g.y + bt.y;
  const float o2 = (v.z - mu) * rstd * g.z + bt.z;
  const float o3 = (v.w - mu) * rstd * g.w + bt.w;
  uint32_t* dst = reinterpret_cast<uint32_t*>(xn + (size_t)row * DIM + tid * 4);
  dst[0] = pack2(o0, o1);
  dst[1] = pack2(o2, o3);
}

// ---------------------------------------------------------------- GEMM (NT: C = A @ W^T)
template<int EPI>
__device__ __forceinline__ void gemm_body(
    const uint16_t* __restrict__ A, const uint16_t* __restrict__ W,
    const float* __restrict__ bias,
    uint16_t* __restrict__ Cb, float* __restrict__ Cf,
    const float* __restrict__ res, float scale)
{
  __shared__ uint16_t As[128 * 32];
  __shared__ uint16_t Bs[128 * 32];
  const int tid  = threadIdx.x;
  const int lane = tid & 63;
  const int w    = tid >> 6;
  const int wr   = w >> 1, wc = w & 1;
  const int row0 = blockIdx.y * 128;
  const int col0 = blockIdx.x * 128;

  f32x4 acc[4][4] = {};

  const int srow = lane >> 2;        // 0..15
  const int scol = (lane & 3) * 8;   // 0,8,16,24
  const uint16_t* a0 = A + (size_t)(row0 + w * 32 + srow) * DIM + scol;
  const uint16_t* a1 = a0 + (size_t)16 * DIM;
  const uint16_t* b0 = W + (size_t)(col0 + w * 32 + srow) * DIM + scol;
  const uint16_t* b1 = b0 + (size_t)16 * DIM;
  uint16_t* la0 = &As[w * 1024];
  uint16_t* la1 = &As[w * 1024 + 512];
  uint16_t* lb0 = &Bs[w * 1024];
  uint16_t* lb1 = &Bs[w * 1024 + 512];

  const int fr = lane & 15, fg = lane >> 4;

  for (int k0 = 0; k0 < DIM; k0 += 32){
    GLDS(a0 + k0, la0);
    GLDS(a1 + k0, la1);
    GLDS(b0 + k0, lb0);
    GLDS(b1 + k0, lb1);
    __syncthreads();
    bf16x8 af[4], bfv[4];
#pragma unroll
    for (int m = 0; m < 4; ++m)
      af[m] = *reinterpret_cast<const bf16x8*>(&As[(wr * 64 + m * 16 + fr) * 32 + fg * 8]);
#pragma unroll
    for (int n = 0; n < 4; ++n)
      bfv[n] = *reinterpret_cast<const bf16x8*>(&Bs[(wc * 64 + n * 16 + fr) * 32 + fg * 8]);
#pragma unroll
    for (int m = 0; m < 4; ++m)
#pragma unroll
      for (int n = 0; n < 4; ++n)
        acc[m][n] = __builtin_amdgcn_mfma_f32_16x16x32_bf16(af[m], bfv[n], acc[m][n], 0, 0, 0);
    __syncthreads();
  }

#pragma unroll
  for (int m = 0; m < 4; ++m){
    const int rbase = row0 + wr * 64 + m * 16 + fg * 4;
#pragma unroll
    for (int n = 0; n < 4; ++n){
      const int c = col0 + wc * 64 + n * 16 + fr;
      const float bv = bias[c];
      if (EPI == 0){
#pragma unroll
        for (int r = 0; r < 4; ++r){
          float v = (acc[m][n][r] + bv) * scale;
          Cb[(size_t)(rbase + r) * DIM + c] = (uint16_t)bf16rnd(v);
        }
      } else {
#pragma unroll
        for (int r = 0; r < 4; ++r){
          size_t idx = (size_t)(rbase + r) * DIM + c;
          Cf[idx] = acc[m][n][r] + bv + res[idx];
        }
      }
    }
  }
}

__global__ __launch_bounds__(256) void qkv_gemm(
    const uint16_t* __restrict__ xn,
    const uint16_t* __restrict__ Wq, const uint16_t* __restrict__ Wk,
    const uint16_t* __restrict__ Wv,
    const float* __restrict__ bq, const float* __restrict__ bk,
    const float* __restrict__ bv,
    uint16_t* __restrict__ Qo, uint16_t* __restrict__ Ko, uint16_t* __restrict__ Vo)
{
  const uint16_t* W; const float* bias; uint16_t* out; float scale;
  if (blockIdx.z == 0){ W = Wq; bias = bq; out = Qo; scale = 0.125f; }  // 1/sqrt(hd) folded into Q
  else if (blockIdx.z == 1){ W = Wk; bias = bk; out = Ko; scale = 1.0f; }
  else { W = Wv; bias = bv; out = Vo; scale = 1.0f; }
  gemm_body<0>(xn, W, bias, out, nullptr, nullptr, scale);
}

__global__ __launch_bounds__(256) void out_gemm(
    const uint16_t* __restrict__ AO, const uint16_t* __restrict__ Wo,
    const float* __restrict__ bo, const float* __restrict__ res,
    float* __restrict__ out)
{
  gemm_body<1>(AO, Wo, bo, nullptr, out, res, 1.0f);
}

// ---------------------------------------------------------------- causal flash attention
// R6 structure with the spill fixed: no min-waves clamp (launch_bounds 256),
// V staging packed into uint64_t[4] at load time (8 VGPRs vs 16).
// Keeps: length-mixing p-swizzle, hoisted K-frags, b64 V-writes, cvt_pk,
// T13 defer-max, T14 async-stage.
__global__ __launch_bounds__(256) void attn_kernel(
    const uint16_t* __restrict__ Q, const uint16_t* __restrict__ K,
    const uint16_t* __restrict__ V, uint16_t* __restrict__ O)
{
  __shared__ uint16_t Kl[64 * 72];
  __shared__ uint16_t Vt[64 * 72];
  const int tid  = threadIdx.x;
  const int lane = tid & 63;
  const int w    = tid >> 6;
  const int fr   = lane & 15, fg = lane >> 4;
  const int b = blockIdx.z, h = blockIdx.y;
  const int p = (blockIdx.x + 4 * blockIdx.z) & 15;   // length-mixing swizzle
  const int qtA = p, qtB = 31 - p;
  const size_t rowb = (size_t)b * TLEN;
  const int hoff = h * HD;

  const int qgA = qtA * 64 + w * 16 + fr;
  const int qgB = qtB * 64 + w * 16 + fr;

  const bf16x8 qA0 = *reinterpret_cast<const bf16x8*>(Q + (rowb + qgA) * DIM + hoff + fg * 8);
  const bf16x8 qA1 = *reinterpret_cast<const bf16x8*>(Q + (rowb + qgA) * DIM + hoff + 32 + fg * 8);
  const bf16x8 qB0 = *reinterpret_cast<const bf16x8*>(Q + (rowb + qgB) * DIM + hoff + fg * 8);
  const bf16x8 qB1 = *reinterpret_cast<const bf16x8*>(Q + (rowb + qgB) * DIM + hoff + 32 + fg * 8);

  f32x4 oA[4] = {}, oB[4] = {};
  float mA = -1e30f, lA = 0.0f, mB = -1e30f, lB = 0.0f;

  const int kr = tid >> 2, kc = (tid & 3) * 16;   // K staging
  const int vd = tid & 63, vq = tid >> 6;         // V staging (transpose)
  const int vf = ((vd >> 3) & 7) << 3;            // write-side swizzle

  const uint16_t* kbase = K + (rowb + kr) * DIM + hoff + kc;
  const uint16_t* vbase = V + (rowb + vq * 16) * DIM + hoff + vd;

  bf16x8 kst0, kst1;
  uint64_t vst[4];

  auto load_tile = [&](int kt, bf16x8& k0, bf16x8& k1, uint64_t (&vr)[4]){
    const size_t koff = (size_t)kt * 64 * DIM;
    k0 = *reinterpret_cast<const bf16x8*>(kbase + koff);
    k1 = *reinterpret_cast<const bf16x8*>(kbase + koff + 8);
    const uint16_t* vsrc = vbase + koff;
#pragma unroll
    for (int j = 0; j < 4; ++j){
      vr[j] = (uint64_t)vsrc[(size_t)(4 * j) * DIM]
            | ((uint64_t)vsrc[(size_t)(4 * j + 1) * DIM] << 16)
            | ((uint64_t)vsrc[(size_t)(4 * j + 2) * DIM] << 32)
            | ((uint64_t)vsrc[(size_t)(4 * j + 3) * DIM] << 48);
    }
  };

  load_tile(0, kst0, kst1, vst);

  for (int kt = 0; kt <= qtB; ++kt){
    const int kv0 = kt * 64;
    // write staged registers to LDS (V as 4 x b64; XOR bits>=3 keep 4-u16 runs contiguous)
    *reinterpret_cast<bf16x8*>(&Kl[kr * 72 + kc])     = kst0;
    *reinterpret_cast<bf16x8*>(&Kl[kr * 72 + kc + 8]) = kst1;
#pragma unroll
    for (int j = 0; j < 4; ++j)
      *reinterpret_cast<uint64_t*>(&Vt[vd * 72 + ((vq * 16 + 4 * j) ^ vf)]) = vst[j];
    __syncthreads();

    // issue next tile's global loads (latency hidden under compute)
    bf16x8 nk0, nk1;
    uint64_t nv[4];
    if (kt < qtB) load_tile(kt + 1, nk0, nk1, nv);

    // K fragments hoisted: shared by both q-steps this iteration
    bf16x8 kf0[4], kf1[4];
#pragma unroll
    for (int t = 0; t < 4; ++t){
      kf0[t] = *reinterpret_cast<const bf16x8*>(&Kl[(t * 16 + fr) * 72 + fg * 8]);
      kf1[t] = *reinterpret_cast<const bf16x8*>(&Kl[(t * 16 + fr) * 72 + 32 + fg * 8]);
    }

    auto step = [&](const bf16x8& q0, const bf16x8& q1, f32x4 (&oacc)[4],
                    float& mr, float& lr, const int qg, const bool diag){
      f32x4 s[4];
#pragma unroll
      for (int t = 0; t < 4; ++t){
        f32x4 z = {};
        z = __builtin_amdgcn_mfma_f32_16x16x32_bf16(kf0[t], q0, z, 0, 0, 0);
        z = __builtin_amdgcn_mfma_f32_16x16x32_bf16(kf1[t], q1, z, 0, 0, 0);
        s[t] = z;
      }

      float mloc = -1e30f;
      if (diag){
#pragma unroll
        for (int t = 0; t < 4; ++t)
#pragma unroll
          for (int r = 0; r < 4; ++r){
            const int kvg = kv0 + t * 16 + fg * 4 + r;
            const float sv = (kvg <= qg) ? s[t][r] : -1e30f;
            s[t][r] = sv;
            mloc = fmaxf(mloc, sv);
          }
      } else {
#pragma unroll
        for (int t = 0; t < 4; ++t)
#pragma unroll
          for (int r = 0; r < 4; ++r) mloc = fmaxf(mloc, s[t][r]);
      }
      mloc = fmaxf(mloc, __shfl_xor(mloc, 16));
      mloc = fmaxf(mloc, __shfl_xor(mloc, 32));

      // T13 defer-max: only rescale when the max moved by > 8
      if (mloc > mr + 8.0f){
        const float alpha = __expf(mr - mloc);
        mr = mloc;
        lr *= alpha;
#pragma unroll
        for (int dt = 0; dt < 4; ++dt) oacc[dt] *= alpha;
      }

      uint32_t plo[4], phi[4];
      float psum = 0.0f;
#pragma unroll
      for (int t = 0; t < 4; ++t){
        const float p0 = __expf(s[t][0] - mr);
        const float p1 = __expf(s[t][1] - mr);
        const float p2 = __expf(s[t][2] - mr);
        const float p3 = __expf(s[t][3] - mr);
        psum += (p0 + p1) + (p2 + p3);
        plo[t] = pack2(p0, p1);
        phi[t] = pack2(p2, p3);
      }
      psum += __shfl_xor(psum, 16);
      psum += __shfl_xor(psum, 32);
      lr += psum;

      // P^T B-fragments via cross-lane redistribution (8 shuffles per 32-kv block)
      const int  src0 = fr + ((lane >> 4) & 1) * 32;
      const bool hi   = lane >= 32;
#pragma unroll
      for (int kb = 0; kb < 2; ++kb){
        const uint32_t la  = (uint32_t)__shfl((int)plo[2 * kb],     src0);
        const uint32_t lb  = (uint32_t)__shfl((int)plo[2 * kb + 1], src0);
        const uint32_t ha  = (uint32_t)__shfl((int)phi[2 * kb],     src0);
        const uint32_t hb  = (uint32_t)__shfl((int)phi[2 * kb + 1], src0);
        const uint32_t la2 = (uint32_t)__shfl((int)plo[2 * kb],     src0 + 16);
        const uint32_t lb2 = (uint32_t)__shfl((int)plo[2 * kb + 1], src0 + 16);
        const uint32_t ha2 = (uint32_t)__shfl((int)phi[2 * kb],     src0 + 16);
        const uint32_t hb2 = (uint32_t)__shfl((int)phi[2 * kb + 1], src0 + 16);
        PFrag pf;
        pf.w[0] = hi ? lb  : la;
        pf.w[1] = hi ? hb  : ha;
        pf.w[2] = hi ? lb2 : la2;
        pf.w[3] = hi ? hb2 : ha2;
#pragma unroll
        for (int dt = 0; dt < 4; ++dt){
          const int d = dt * 16 + fr;
          const int f = ((d >> 3) & 7) << 3;
          const bf16x8 vfr = *reinterpret_cast<const bf16x8*>(
              &Vt[d * 72 + ((kb * 32 + fg * 8) ^ f)]);
          oacc[dt] = __builtin_amdgcn_mfma_f32_16x16x32_bf16(vfr, pf.v, oacc[dt], 0, 0, 0);
        }
      }
    };

    if (kt <= qtA) step(qA0, qA1, oA, mA, lA, qgA, kt == qtA);
    step(qB0, qB1, oB, mB, lB, qgB, kt == qtB);
    __syncthreads();

    if (kt < qtB){
      kst0 = nk0; kst1 = nk1;
#pragma unroll
      for (int j = 0; j < 4; ++j) vst[j] = nv[j];
    }
  }

  const float invA = 1.0f / lA;
  const float invB = 1.0f / lB;
#pragma unroll
  for (int dt = 0; dt < 4; ++dt){
    uint32_t* dstA = reinterpret_cast<uint32_t*>(
        O + (rowb + qgA) * DIM + hoff + dt * 16 + fg * 4);
    dstA[0] = pack2(oA[dt][0] * invA, oA[dt][1] * invA);
    dstA[1] = pack2(oA[dt][2] * invA, oA[dt][3] * invA);
    uint32_t* dstB = reinterpret_cast<uint32_t*>(
        O + (rowb + qgB) * DIM + hoff + dt * 16 + fg * 4);
    dstB[0] = pack2(oB[dt][0] * invB, oB[dt][1] * invB);
    dstB[1] = pack2(oB[dt][2] * invB, oB[dt][3] * invB);
  }
}

// ---------------------------------------------------------------- launch
extern "C" void kernel_launch(void* const* d_in, const int* in_sizes, int n_in,
                              void* d_out, int out_size, void* d_ws, size_t ws_size,
                              hipStream_t stream) {
  const float* x     = (const float*)d_in[0];
  const float* Wq    = (const float*)d_in[1];
  const float* bq    = (const float*)d_in[2];
  const float* Wk    = (const float*)d_in[3];
  const float* bk    = (const float*)d_in[4];
  const float* Wv    = (const float*)d_in[5];
  const float* bv    = (const float*)d_in[6];
  const float* Wo    = (const float*)d_in[7];
  const float* bo    = (const float*)d_in[8];
  const float* gamma = (const float*)d_in[9];
  const float* beta  = (const float*)d_in[10];
  float* out = (float*)d_out;

  uint8_t* ws = (uint8_t*)d_ws;
  uint16_t* xn  = (uint16_t*)(ws);                                  // 16 MB
  uint16_t* Wqb = (uint16_t*)(ws + 16777216);                       // 2 MB each
  uint16_t* Wkb = (uint16_t*)(ws + 16777216 + 1 * 2097152);
  uint16_t* Wvb = (uint16_t*)(ws + 16777216 + 2 * 2097152);
  uint16_t* Wob = (uint16_t*)(ws + 16777216 + 3 * 2097152);
  uint16_t* Qb  = (uint16_t*)(ws + 25165824);                       // 16 MB each
  uint16_t* Kb  = (uint16_t*)(ws + 25165824 + 1 * 16777216);
  uint16_t* Vb  = (uint16_t*)(ws + 25165824 + 2 * 16777216);
  uint16_t* AOb = (uint16_t*)(ws + 25165824 + 3 * 16777216);

  cvt_kernel<<<dim3(1024, 4), 256, 0, stream>>>(Wq, Wk, Wv, Wo, Wqb, Wkb, Wvb, Wob);
  ln_kernel<<<8192, 256, 0, stream>>>(x, gamma, beta, xn);
  qkv_gemm<<<dim3(8, 64, 3), 256, 0, stream>>>(xn, Wqb, Wkb, Wvb, bq, bk, bv, Qb, Kb, Vb);
  attn_kernel<<<dim3(16, 16, 4), 256, 0, stream>>>(Qb, Kb, Vb, AOb);
  out_gemm<<<dim3(8, 64, 1), 256, 0, stream>>>(AOb, Wob, bo, x, out);
}